// Round 1
// baseline (24.445 us; speedup 1.0000x reference)
//
#include <hip/hip_runtime.h>

constexpr int DIM = 32;
constexpr int NKS = 50;

// One batch element per 8-lane group: lane L holds float4 #L of each 32-float
// row (128 B coalesced per group). Lorentz signs are folded into the anchor
// fragment so the cross-lane reduce is a plain 3-step xor-shuffle sum.
__global__ __launch_bounds__(256)
void lorentz_loss_kernel(const float* __restrict__ table,
                         const int* __restrict__ I,
                         const int* __restrict__ Ks,
                         float* __restrict__ out, int B)
{
    const int lane8 = threadIdx.x & 7;
    const int group = threadIdx.x >> 3;           // 0..31 within block
    const int b     = blockIdx.x * 32 + group;
    if (b >= B) return;

    const float4* __restrict__ tab4 = reinterpret_cast<const float4*>(table);

    const long long i0 = I[b];
    const float4 u = tab4[i0 * (DIM / 4) + lane8];

    // d = u[0]*k[0] - sum_{d>=1} u[d]*k[d]  -> sign-fold into anchor
    float4 us;
    us.x = (lane8 == 0) ? u.x : -u.x;
    us.y = -u.y;
    us.z = -u.z;
    us.w = -u.w;

    const int* __restrict__ ks = Ks + (long long)b * NKS;

    float d0 = 0.0f;
    float sumexp = 0.0f;

#pragma unroll 5
    for (int n = 0; n < NKS; ++n) {
        const long long k = ks[n];
        const float4 v4 = tab4[k * (DIM / 4) + lane8];

        float p = us.x * v4.x + us.y * v4.y + us.z * v4.z + us.w * v4.w;
        p += __shfl_xor(p, 4, 8);
        p += __shfl_xor(p, 2, 8);
        p += __shfl_xor(p, 1, 8);

        float dd  = (p <= 1.0f) ? 1.000001f : p;
        float arc = -logf(dd + sqrtf(dd * dd - 1.0f));

        d0 = (n == 0) ? arc : d0;
        sumexp += expf(arc);
    }

    if (lane8 == 0)
        out[b] = -(d0 - logf(sumexp + 1e-6f));
}

extern "C" void kernel_launch(void* const* d_in, const int* in_sizes, int n_in,
                              void* d_out, int out_size, void* d_ws, size_t ws_size,
                              hipStream_t stream) {
    const float* table = (const float*)d_in[0];
    const int*   I     = (const int*)d_in[1];
    const int*   Ks    = (const int*)d_in[2];
    float*       out   = (float*)d_out;

    const int B = in_sizes[1];                    // 16384 anchors
    const int blocks = (B + 31) / 32;             // 32 elements per 256-thread block

    lorentz_loss_kernel<<<blocks, 256, 0, stream>>>(table, I, Ks, out, B);
}

// Round 2
// 24.245 us; speedup vs baseline: 1.0082x; 1.0082x over previous
//
#include <hip/hip_runtime.h>

constexpr int DIM = 32;
constexpr int NKS = 50;

// One wave (64 lanes) per batch element.
//   lane = g*8 + l : group g in [0,8) handles pairs n = g + 8*t (t = 0..6),
//   lane-within-group l holds float4 slot l of each 32-float row (128 B row
//   read = one coalesced cache line per 8-lane group).
// All 50 Ks indices are pre-loaded (one per lane, n = g + 8*l) and broadcast
// per iteration with __shfl(kn, t, 8), so every row gather in the t-loop is
// address-independent -> ~7 loads in flight per lane.
// exp(-arcosh(d)) == 1/(d + sqrt(d^2-1)) kills the per-pair exp/log.
__global__ __launch_bounds__(256)
void lorentz_loss_kernel(const float* __restrict__ table,
                         const int* __restrict__ I,
                         const int* __restrict__ Ks,
                         float* __restrict__ out, int B)
{
    const int lane  = threadIdx.x & 63;
    const int lane8 = lane & 7;            // float4 slot within row
    const int group = lane >> 3;           // n-stride subset
    const int b     = blockIdx.x * 4 + (threadIdx.x >> 6);
    if (b >= B) return;

    const float4* __restrict__ tab4 = reinterpret_cast<const float4*>(table);

    const int i0 = I[b];
    const float4 u = tab4[(long long)i0 * 8 + lane8];

    // Lorentz sign fold: d = u0*v0 - sum_{i>=1} ui*vi
    float4 us;
    us.x = (lane8 == 0) ? u.x : -u.x;
    us.y = -u.y;
    us.z = -u.z;
    us.w = -u.w;

    // Pre-load this wave's Ks row: lane (g,l) holds index for n = g + 8*l.
    const int n_pre = group + 8 * lane8;
    const int kn = (n_pre < NKS) ? Ks[(long long)b * NKS + n_pre] : 0;

    float sum = 0.0f;
    float t0  = 1.0f;   // t for n==0 (lives on group 0's lanes)

#pragma unroll
    for (int t = 0; t < 7; ++t) {
        const int n = group + 8 * t;
        if (n < NKS) {
            const int k = __shfl(kn, t, 8);
            const float4 v = tab4[(long long)k * 8 + lane8];

            float p = us.x * v.x + us.y * v.y + us.z * v.z + us.w * v.w;
            p += __shfl_xor(p, 4, 8);
            p += __shfl_xor(p, 2, 8);
            p += __shfl_xor(p, 1, 8);

            const float dd = (p <= 1.0f) ? 1.000001f : p;
            const float tt = dd + sqrtf(dd * dd - 1.0f);
            sum += __builtin_amdgcn_rcpf(tt);   // = exp(-arcosh(dd)), 1-ulp
            if (n == 0) t0 = tt;                // only group 0, t==0
        }
    }

    // Combine the 8 group-partials (groups are lane bits 3..5).
    sum += __shfl_xor(sum, 8);
    sum += __shfl_xor(sum, 16);
    sum += __shfl_xor(sum, 32);

    if (lane == 0)
        out[b] = logf(t0) + logf(sum + 1e-6f);  // == -(d0 - log(sumexp+1e-6))
}

extern "C" void kernel_launch(void* const* d_in, const int* in_sizes, int n_in,
                              void* d_out, int out_size, void* d_ws, size_t ws_size,
                              hipStream_t stream) {
    const float* table = (const float*)d_in[0];
    const int*   I     = (const int*)d_in[1];
    const int*   Ks    = (const int*)d_in[2];
    float*       out   = (float*)d_out;

    const int B = in_sizes[1];                 // 16384 anchors
    const int blocks = (B + 3) / 4;            // 4 elements (waves) per block

    lorentz_loss_kernel<<<blocks, 256, 0, stream>>>(table, I, Ks, out, B);
}